// Round 23
// baseline (318.535 us; speedup 1.0000x reference)
//
#include <hip/hip_runtime.h>
#include <hip/hip_bf16.h>

#define BB 32
#define NN 8192
#define KK 64
#define OUTC 384
#define EPSB 1e-5f

// k_out LDS row strides (bf16 rows padded +16B to kill bank conflicts linearly)
#define AS_STRIDE 528     // 256 bf16 = 512B + 16B pad
#define MH_STRIDE 528     // Mid half: 256 bf16 = 512B + 16B pad

typedef short bf16x8 __attribute__((ext_vector_type(8)));
typedef float f32x4 __attribute__((ext_vector_type(4)));
typedef unsigned int u32x2 __attribute__((ext_vector_type(2)));
typedef unsigned int u32x4 __attribute__((ext_vector_type(4)));

static __device__ __forceinline__ unsigned short f2b(float x) {
  union { float f; unsigned int u; } v; v.f = x;
  unsigned int r = v.u + 0x7FFFu + ((v.u >> 16) & 1u);
  return (unsigned short)(r >> 16);
}
static __device__ __forceinline__ float b2f(unsigned short h) {
  union { unsigned int u; float f; } v; v.u = ((unsigned int)h) << 16;
  return v.f;
}
// pack 2 f32 -> 2 bf16 in one u32 (RNE, matches f2b)
static __device__ __forceinline__ unsigned int cvtpk(float lo, float hi) {
  unsigned int r;
  asm("v_cvt_pk_bf16_f32 %0, %1, %2" : "=v"(r) : "v"(lo), "v"(hi));
  return r;
}

// ---------------- prep: fold BN into weights, convert to bf16 ----------------
// W2b/W3s/W4b stored FRAGMENT-MAJOR: 1KB blocks = one 16x32 MFMA operand frag,
// lane l's bf16x8 at frag*512 + l*8 elems (l = (kchunk<<4) | row_local).
__global__ void prep(const float* W1, const float* b1, const float* g1, const float* be1,
                     const float* m1, const float* v1,
                     const float* W2, const float* W3, const float* b3, const float* W4,
                     const float* g2, const float* be2, const float* m2, const float* v2,
                     float* W1f, float* bco,
                     unsigned short* W2b, unsigned short* W3s, unsigned short* W3ls,
                     unsigned short* W4b)
{
  int i = blockIdx.x * blockDim.x + threadIdx.x;
  int T = gridDim.x * blockDim.x;
  for (int d = i; d < 128; d += T) {
    float s1 = g1[d] / sqrtf(v1[d] + EPSB);
    W1f[d*4+0] = s1 * W1[d*3+0];
    W1f[d*4+1] = s1 * W1[d*3+1];
    W1f[d*4+2] = s1 * W1[d*3+2];
    W1f[d*4+3] = s1 * (b1[d] - m1[d]) + be1[d];
  }
  for (int n = i; n < 512; n += T) {
    float s = g2[n] / sqrtf(v2[n] + EPSB);
    bco[n] = s * b3[n] + be2[n] - s * m2[n];   // BN2 shift + scaled conv bias
  }
  for (int x = i; x < 256*128; x += T) {
    int c = x >> 7, kk = x & 127;
    int lane = (((kk & 31) >> 3) << 4) | (c & 15);
    int frag = (c >> 4) * 4 + (kk >> 5);
    W2b[frag*512 + lane*8 + (kk & 7)] = f2b(W2[x]);
  }
  for (int x = i; x < 512*256; x += T) {
    int n = x >> 8, kk = x & 255;
    float s = g2[n] / sqrtf(v2[n] + EPSB);
    int lane = (((kk & 31) >> 3) << 4) | (n & 15);
    int frag = (n >> 4) * 8 + (kk >> 5);
    W3s[frag*512 + lane*8 + (kk & 7)] = f2b(s * W3[n*512 + 256 + kk]);
    W3ls[x] = f2b(s * W3[n*512 + kk]);         // left half, row-major (k_dv)
  }
  for (int x = i; x < 384*512; x += T) {
    int n = x >> 9, kk = x & 511;
    int lane = (((kk & 31) >> 3) << 4) | (n & 15);
    int frag = (n >> 4) * 16 + (kk >> 5);
    W4b[frag*512 + lane*8 + (kk & 7)] = f2b(W4[x]);
  }
}

// ---------------- sortk: per-batch counting sort of points by cluster -------
__global__ void sortk(const int* __restrict__ choice, int* __restrict__ ord,
                      int* __restrict__ seg)
{
  int b = blockIdx.x;
  int t = threadIdx.x;
  __shared__ int hist[KK];
  __shared__ int base[KK];
  if (t < KK) hist[t] = 0;
  __syncthreads();
  for (int i = t; i < NN; i += blockDim.x) atomicAdd(&hist[choice[b*NN + i]], 1);
  __syncthreads();
  if (t == 0) {
    int acc = 0;
    for (int k = 0; k < KK; ++k) { base[k] = acc; seg[b*(KK+1)+k] = acc; acc += hist[k]; }
    seg[b*(KK+1)+KK] = acc;   // == NN
  }
  __syncthreads();
  for (int i = t; i < NN; i += blockDim.x) {
    int c = choice[b*NN + i];
    int pos = atomicAdd(&base[c], 1);
    ord[b*NN + pos] = i;
  }
}

// ---------------- k_feat: xyz -> h128 (BN,ReLU) -> feat 256 (bf16, sorted) --
// GEMM2 swapped; outputs staged in LDS hO then flushed lane-contiguous:
// each wave store instruction covers one 1KB contiguous global segment.
__global__ __launch_bounds__(256) void k_feat(const float* __restrict__ xyz,
                                              const int* __restrict__ ord,
                                              const float* __restrict__ W1f,
                                              const unsigned short* __restrict__ W2b,
                                              const float* __restrict__ b2,
                                              unsigned short* __restrict__ feat)
{
  __shared__ float lW1[128*4];
  __shared__ __align__(16) char hA[64*256];   // 64 rows x 128 bf16, XOR-swizzled
  __shared__ __align__(16) char hO[64*512];   // 64 rows x 256 bf16, XOR-swizzled
  int t = threadIdx.x;
  int b = blockIdx.x >> 7;            // 128 blocks per batch
  int posbase = (blockIdx.x & 127) * 64;
  if (t < 128) ((f32x4*)lW1)[t] = ((const f32x4*)W1f)[t];
  __syncthreads();

  {
    int r = t >> 2;
    int q = t & 3;
    int p = ord[b*NN + posbase + r];
    const float* xp = xyz + (size_t)(b*NN + p)*3;
    float x0 = xp[0], x1 = xp[1], x2 = xp[2];
#pragma unroll
    for (int dd = 0; dd < 32; dd += 2) {
      int d = q*32 + dd;
      f32x4 w0 = ((const f32x4*)lW1)[d];
      f32x4 w1 = ((const f32x4*)lW1)[d+1];
      float v0 = fmaxf(fmaf(x2, w0[2], fmaf(x1, w0[1], fmaf(x0, w0[0], w0[3]))), 0.0f);
      float v1 = fmaxf(fmaf(x2, w1[2], fmaf(x1, w1[1], fmaf(x0, w1[0], w1[3]))), 0.0f);
      unsigned int pk = cvtpk(v0, v1);
      int byte = ((r*128 + d)*2) ^ ((r & 7) << 4);
      *(unsigned int*)(hA + byte) = pk;
    }
  }
  __syncthreads();

  int lane = t & 63, w = t >> 6;
  int lrow = lane & 15, lhi = lane >> 4;
  f32x4 acc[4][4];   // [cf][pf]
#pragma unroll
  for (int cf = 0; cf < 4; ++cf)
#pragma unroll
    for (int pf = 0; pf < 4; ++pf) acc[cf][pf] = (f32x4)0.0f;

#pragma unroll
  for (int ks = 0; ks < 4; ++ks) {
    int k0 = ks*32 + lhi*8;
    bf16x8 haf[4];
#pragma unroll
    for (int pf = 0; pf < 4; ++pf) {
      int row = pf*16 + lrow;
      int byte = ((row*128 + k0)*2) ^ ((row & 7) << 4);
      haf[pf] = *(const bf16x8*)(hA + byte);
    }
    bf16x8 wf[4];
#pragma unroll
    for (int cf = 0; cf < 4; ++cf) {
      int frag = ((w*4 + cf)*4 + ks);
      wf[cf] = *(const bf16x8*)(W2b + frag*512 + lane*8);
    }
#pragma unroll
    for (int cf = 0; cf < 4; ++cf)
#pragma unroll
      for (int pf = 0; pf < 4; ++pf)
        acc[cf][pf] = __builtin_amdgcn_mfma_f32_16x16x32_bf16(wf[cf], haf[pf], acc[cf][pf], 0, 0, 0);
  }

  // epilogue: lane holds c = w*64+cf*16+4*lhi+rr at point pf*16+lrow -> hO LDS
#pragma unroll
  for (int cf = 0; cf < 4; ++cf) {
    int c0 = w*64 + cf*16 + 4*lhi;
    f32x4 bv = *(const f32x4*)(b2 + c0);
#pragma unroll
    for (int pf = 0; pf < 4; ++pf) {
      int row = pf*16 + lrow;
      u32x2 pk;
      pk[0] = cvtpk(acc[cf][pf][0] + bv[0], acc[cf][pf][1] + bv[1]);
      pk[1] = cvtpk(acc[cf][pf][2] + bv[2], acc[cf][pf][3] + bv[3]);
      int byte = (row*512 + c0*2) ^ ((row & 7) << 4);
      *(u32x2*)(hO + byte) = pk;
    }
  }
  __syncthreads();

  // lane-contiguous flush: instr cc of wave w covers 1KB contiguous global
  // (lin = w*8KB + cc*1KB + lane*16B); block covers the full 32KB tile.
#pragma unroll
  for (int cc = 0; cc < 8; ++cc) {
    int lin = w*8192 + cc*1024 + lane*16;
    int row = lin >> 9;
    int off = lin & 511;
    int src = (row*512 + off) ^ ((row & 7) << 4);
    u32x4 v = *(const u32x4*)(hO + src);
    __builtin_nontemporal_store(v,
        (u32x4*)((char*)(feat + (size_t)(b*NN + posbase + row)*256) + off));
  }
}

// ---------------- k_fg: per-(b,k) max over cluster points -> fg bf16 --------
// 8 rows x 32 channel-groups: 16B loads per lane (wave covers 2x512B segs);
// cross-row reduce via tiny one-shot LDS pass.
__global__ __launch_bounds__(256) void k_fg(const unsigned short* __restrict__ feat,
                                            const int* __restrict__ seg,
                                            unsigned short* __restrict__ fg)
{
  __shared__ float red[8][256];
  int blk = blockIdx.x;
  int b = blk >> 6, k = blk & 63;
  int s = seg[b*(KK+1)+k], e = seg[b*(KK+1)+k+1];
  int t = threadIdx.x;
  int rg = t >> 5;          // 0..7: row within 8-row chunk
  int cg = t & 31;          // 0..31: channel group (8 ch = 16B)
  float m[8];
#pragma unroll
  for (int j = 0; j < 8; ++j) m[j] = -1e30f;
  for (int i = s + rg; i < e; i += 8) {
    u32x4 v = __builtin_nontemporal_load(
        (const u32x4*)(feat + (size_t)(b*NN + i)*256 + cg*8));
#pragma unroll
    for (int j = 0; j < 4; ++j) {
      unsigned int u = v[j];
      m[2*j]   = fmaxf(m[2*j],   b2f((unsigned short)(u & 0xffffu)));
      m[2*j+1] = fmaxf(m[2*j+1], b2f((unsigned short)(u >> 16)));
    }
  }
#pragma unroll
  for (int j = 0; j < 8; ++j) red[rg][cg*8 + j] = m[j];
  __syncthreads();
  float mm = red[0][t];
#pragma unroll
  for (int j = 1; j < 8; ++j) mm = fmaxf(mm, red[j][t]);
  fg[(b*KK + k)*256 + t] = f2b(mm);
}

// ---------------- k_dv: Dv[2048][512] = fg @ W3ls^T + bco (MFMA GEMM) -------
__global__ __launch_bounds__(256) void k_dv(const unsigned short* __restrict__ fg,
                                            const unsigned short* __restrict__ W3ls,
                                            const float* __restrict__ bco,
                                            float* __restrict__ Dv)
{
  __shared__ __align__(16) char As[32*512];   // 32 rows x 256 bf16, swizzled
  int t = threadIdx.x;
  int row0 = blockIdx.x * 32;
  {
    int r = t >> 3;
    const char* src = (const char*)(fg + (size_t)(row0 + r)*256);
    int cbase = (t & 7) * 16;
#pragma unroll
    for (int cc = 0; cc < 4; ++cc) {
      int byteoff = cbase + cc*128;
      int dst = (r*512 + byteoff) ^ ((r & 7) << 4);
      *(u32x4*)(As + dst) = *(const u32x4*)(src + byteoff);
    }
  }
  __syncthreads();

  int lane = t & 63, w = t >> 6;
  int lrow = lane & 15, lhi = lane >> 4;

  f32x4 acc[2][8];
#pragma unroll
  for (int m = 0; m < 2; ++m)
#pragma unroll
    for (int nt = 0; nt < 8; ++nt) acc[m][nt] = (f32x4)0.0f;

#pragma unroll 2
  for (int ks = 0; ks < 8; ++ks) {
    int koff = ks*32 + lhi*8;
    bf16x8 af[2];
#pragma unroll
    for (int m = 0; m < 2; ++m) {
      int row = m*16 + lrow;
      int byte = (row*512 + koff*2) ^ ((row & 7) << 4);
      af[m] = *(const bf16x8*)(As + byte);
    }
    bf16x8 bf[8];
#pragma unroll
    for (int nt = 0; nt < 8; ++nt) {
      int n = w*128 + nt*16 + lrow;
      bf[nt] = *(const bf16x8*)(W3ls + n*256 + koff);
    }
#pragma unroll
    for (int m = 0; m < 2; ++m)
#pragma unroll
      for (int nt = 0; nt < 8; ++nt)
        acc[m][nt] = __builtin_amdgcn_mfma_f32_16x16x32_bf16(af[m], bf[nt], acc[m][nt], 0, 0, 0);
  }

#pragma unroll
  for (int m = 0; m < 2; ++m)
#pragma unroll
    for (int nt = 0; nt < 8; ++nt) {
      int n = w*128 + nt*16 + lrow;
      float bc = bco[n];
#pragma unroll
      for (int rr = 0; rr < 4; ++rr) {
        int row = m*16 + lhi*4 + rr;
        Dv[(size_t)(row0 + row)*512 + n] = acc[m][nt][rr] + bc;
      }
    }
}

// ---------------- k_out: per-(b,k) fused GEMM3' + BN + ReLU + GEMM4 + max ---
// 512 threads (8 waves), M=48, VGPR<=64, SPLIT-MID through one 24.75KB
// half-buffer: bar -> G3A -> bar -> G4A -> bar -> G3B -> bar -> stage -> G4B.
// LDS = 53KB -> 3 blocks/CU (24 waves/CU) for latency overlap; acc4 carries
// across the two G4 passes in VGPRs.
__global__ __launch_bounds__(512, 8) void k_out(const unsigned short* __restrict__ feat,
                                                const int* __restrict__ seg,
                                                const float* __restrict__ Dv,
                                                const unsigned short* __restrict__ W3s,
                                                const unsigned short* __restrict__ W4b,
                                                const float* __restrict__ b4,
                                                float* __restrict__ out)
{
  __shared__ float Dvs[512];
  __shared__ float rm[OUTC];
  __shared__ __align__(16) char As[48*AS_STRIDE];    // 24.75KB
  __shared__ __align__(16) char MidH[48*MH_STRIDE];  // 24.75KB (one n-half)
  int blk = blockIdx.x;
  int b = blk >> 6, k = blk & 63;
  int t = threadIdx.x;
  int s = seg[b*(KK+1)+k], e = seg[b*(KK+1)+k+1];
  int S = e - s;

  Dvs[t] = Dv[(size_t)(b*KK + k)*512 + t];
  if (t < OUTC) rm[t] = -1e30f;

  int lane = t & 63, w = t >> 6;
  int lrow = lane & 15, lhi = lane >> 4;

  // linear LDS bases (1 VGPR each; all per-access variation is imm offsets)
  int baseA = lrow*AS_STRIDE + lhi*16;                 // G3 As reads
  int baseM = lrow*MH_STRIDE + lhi*16;                 // G4 MidH reads
  int baseW = lrow*MH_STRIDE + w*64 + lhi*8;           // G3 MidH writes (n-local)

  // stage helpers: 48 rows x 32 chunks(16B) = 1536 chunks; 3 per thread
  int lim = b*NN + NN - 1;
  int srow[3], sdst[3], soff[3];
#pragma unroll
  for (int j = 0; j < 3; ++j) {
    int c = t + j*512;
    srow[j] = c >> 5;
    soff[j] = (c & 31) * 16;
    sdst[j] = srow[j]*AS_STRIDE + soff[j];
  }

  // prologue: stage tile 0
#pragma unroll
  for (int j = 0; j < 3; ++j) {
    int pos = b*NN + s + srow[j];
    if (pos > lim) pos = lim;
    const char* src = (const char*)(feat + (size_t)pos*256);
    u32x4 v = __builtin_nontemporal_load((const u32x4*)(src + soff[j]));
    *(u32x4*)(As + sdst[j]) = v;
  }

  for (int mt = 0; mt < S; mt += 48) {
    __syncthreads();   // bar0: As staged; MidH free (prev G4B done)

    f32x4 acc4[3][3];
#pragma unroll
    for (int m = 0; m < 3; ++m)
#pragma unroll
      for (int nt = 0; nt < 3; ++nt) acc4[m][nt] = (f32x4)0.0f;

#pragma unroll 1
    for (int h = 0; h < 2; ++h) {
      // G3 half h: n in [h*256,+256), wave w owns 32 cols; 2 nf frags
      {
        f32x4 acc2[2][3];   // [nf][pf]
#pragma unroll
        for (int nf = 0; nf < 2; ++nf)
#pragma unroll
          for (int pf = 0; pf < 3; ++pf) acc2[nf][pf] = (f32x4)0.0f;

#pragma unroll 1
        for (int ks = 0; ks < 8; ++ks) {
          bf16x8 asf[3];
#pragma unroll
          for (int pf = 0; pf < 3; ++pf)
            asf[pf] = *(const bf16x8*)(As + (baseA + ks*64 + pf*(16*AS_STRIDE)));
          bf16x8 w3f[2];
#pragma unroll
          for (int nf = 0; nf < 2; ++nf) {
            int frag = (h*16 + w*2 + nf)*8 + ks;
            w3f[nf] = *(const bf16x8*)(W3s + frag*512 + lane*8);
          }
          __builtin_amdgcn_s_setprio(1);
#pragma unroll
          for (int nf = 0; nf < 2; ++nf)
#pragma unroll
            for (int pf = 0; pf < 3; ++pf)
              acc2[nf][pf] = __builtin_amdgcn_mfma_f32_16x16x32_bf16(w3f[nf], asf[pf], acc2[nf][pf], 0, 0, 0);
          __builtin_amdgcn_s_setprio(0);
        }

        // epilogue: lane holds nlocal = w*32+nf*16+4*lhi+rr at point pf*16+lrow
#pragma unroll
        for (int nf = 0; nf < 2; ++nf) {
          int nl0 = w*32 + nf*16 + 4*lhi;
          f32x4 d4 = *(const f32x4*)(Dvs + h*256 + nl0);
#pragma unroll
          for (int pf = 0; pf < 3; ++pf) {
            float v0 = fmaxf(acc2[nf][pf][0] + d4[0], 0.0f);
            float v1 = fmaxf(acc2[nf][pf][1] + d4[1], 0.0f);
            float v2 = fmaxf(acc2[nf][pf][2] + d4[2], 0.0f);
            float v3 = fmaxf(acc2[nf][pf][3] + d4[3], 0.0f);
            u32x2 pk;
            pk[0] = cvtpk(v0, v1);
            pk[1] = cvtpk(v2, v3);
            *(u32x2*)(MidH + (baseW + nf*32 + pf*(16*MH_STRIDE))) = pk;
          }
        }
      }
      __syncthreads();   // bar1/bar3: MidH half ready; (h=1: G3B As reads done)

      // h=1: stage tile i+1 into As (As free after G3B's reads; overlaps G4B)
      if (h == 1 && mt + 48 < S) {
#pragma unroll
        for (int j = 0; j < 3; ++j) {
          int pos = b*NN + s + mt + 48 + srow[j];
          if (pos > lim) pos = lim;
          const char* src = (const char*)(feat + (size_t)pos*256);
          u32x4 v = __builtin_nontemporal_load((const u32x4*)(src + soff[j]));
          *(u32x4*)(As + sdst[j]) = v;
        }
      }

      // G4 pass h: K-slice [h*256,+256) from MidH; W4b ks = h*8 + local
#pragma unroll 1
      for (int ks = 0; ks < 8; ++ks) {
        bf16x8 af[3];
#pragma unroll
        for (int m = 0; m < 3; ++m)
          af[m] = *(const bf16x8*)(MidH + (baseM + ks*64 + m*(16*MH_STRIDE)));
        __builtin_amdgcn_s_setprio(1);
#pragma unroll
        for (int nt = 0; nt < 3; ++nt) {
          int frag = (w*3 + nt)*16 + h*8 + ks;
          bf16x8 bf = *(const bf16x8*)(W4b + frag*512 + lane*8);
#pragma unroll
          for (int m = 0; m < 3; ++m)
            acc4[m][nt] = __builtin_amdgcn_mfma_f32_16x16x32_bf16(af[m], bf, acc4[m][nt], 0, 0, 0);
        }
        __builtin_amdgcn_s_setprio(0);
      }

      if (h == 0) __syncthreads();   // bar2: G4A MidH reads done before G3B writes
    }

    // per-tile max: reduce rows of this tile, RMW by owner lane (disjoint cols/wave)
#pragma unroll
    for (int nt = 0; nt < 3; ++nt) {
      float v = -1e30f;
#pragma unroll
      for (int m = 0; m < 3; ++m)
#pragma unroll
        for (int rr = 0; rr < 4; ++rr) {
          int rowg = mt + m*16 + lhi*4 + rr;
          v = (rowg < S) ? fmaxf(v, acc4[m][nt][rr]) : v;
        }
      v = fmaxf(v, __shfl_xor(v, 16, 64));
      v = fmaxf(v, __shfl_xor(v, 32, 64));
      if (lane < 16) {
        int col = w*48 + nt*16 + lrow;
        rm[col] = fmaxf(rm[col], v);
      }
    }
  }
  __syncthreads();

  if (t < OUTC) out[(b*KK + k)*OUTC + t] = rm[t] + b4[t];
}

extern "C" void kernel_launch(void* const* d_in, const int* in_sizes, int n_in,
                              void* d_out, int out_size, void* d_ws, size_t ws_size,
                              hipStream_t stream)
{
  const float* xyz   = (const float*)d_in[0];
  const int*   choice= (const int*)  d_in[1];
  const float* W1    = (const float*)d_in[2];
  const float* b1    = (const float*)d_in[3];
  const float* g1    = (const float*)d_in[4];
  const float* be1   = (const float*)d_in[5];
  const float* m1    = (const float*)d_in[6];
  const float* v1    = (const float*)d_in[7];
  const float* W2    = (const float*)d_in[8];
  const float* b2    = (const float*)d_in[9];
  const float* W3    = (const float*)d_in[10];
  const float* b3    = (const float*)d_in[11];
  const float* g2    = (const float*)d_in[12];
  const float* be2   = (const float*)d_in[13];
  const float* m2    = (const float*)d_in[14];
  const float* v2    = (const float*)d_in[15];
  const float* W4    = (const float*)d_in[16];
  const float* b4    = (const float*)d_in[17];

  char* ws = (char*)d_ws;
  size_t o = 0;
  int* ord             = (int*)(ws + o);            o += (size_t)BB*NN*4;       // 1 MB
  int* seg             = (int*)(ws + o);            o += 64*1024;
  float* W1f           = (float*)(ws + o);          o += 4*1024;
  float* bco           = (float*)(ws + o);          o += 4*1024;
  unsigned short* W2b  = (unsigned short*)(ws + o); o += (size_t)256*128*2;
  unsigned short* W3s  = (unsigned short*)(ws + o); o += (size_t)512*256*2;
  unsigned short* W3ls = (unsigned short*)(ws + o); o += (size_t)512*256*2;
  unsigned short* W4b  = (unsigned short*)(ws + o); o += (size_t)384*512*2;
  unsigned short* fg   = (unsigned short*)(ws + o); o += (size_t)BB*KK*256*2;   // 1 MB
  float* Dv            = (float*)(ws + o);          o += (size_t)BB*KK*512*4;   // 4 MB
  unsigned short* feat = (unsigned short*)(ws + o); o += (size_t)BB*NN*256*2;   // 128 MB

  prep<<<512, 256, 0, stream>>>(W1, b1, g1, be1, m1, v1, W2, W3, b3, W4,
                                g2, be2, m2, v2, W1f, bco, W2b, W3s, W3ls, W4b);
  sortk<<<BB, 256, 0, stream>>>(choice, ord, seg);
  k_feat<<<BB*NN/64, 256, 0, stream>>>(xyz, ord, W1f, W2b, b2, feat);
  k_fg<<<BB*KK, 256, 0, stream>>>(feat, seg, fg);
  k_dv<<<BB*KK/32, 256, 0, stream>>>(fg, W3ls, bco, Dv);
  k_out<<<BB*KK, 512, 0, stream>>>(feat, seg, Dv, W3s, W4b, b4, (float*)d_out);
}

// Round 24
// 315.443 us; speedup vs baseline: 1.0098x; 1.0098x over previous
//
#include <hip/hip_runtime.h>
#include <hip/hip_bf16.h>

#define BB 32
#define NN 8192
#define KK 64
#define OUTC 384
#define EPSB 1e-5f

// k_out LDS row strides (bf16 rows padded +16B to kill bank conflicts linearly)
#define AS_STRIDE 528     // 256 bf16 = 512B + 16B pad
#define MID_STRIDE 1040   // 512 bf16 = 1024B + 16B pad

typedef short bf16x8 __attribute__((ext_vector_type(8)));
typedef float f32x4 __attribute__((ext_vector_type(4)));
typedef unsigned int u32x2 __attribute__((ext_vector_type(2)));
typedef unsigned int u32x4 __attribute__((ext_vector_type(4)));

static __device__ __forceinline__ unsigned short f2b(float x) {
  union { float f; unsigned int u; } v; v.f = x;
  unsigned int r = v.u + 0x7FFFu + ((v.u >> 16) & 1u);
  return (unsigned short)(r >> 16);
}
static __device__ __forceinline__ float b2f(unsigned short h) {
  union { unsigned int u; float f; } v; v.u = ((unsigned int)h) << 16;
  return v.f;
}
// pack 2 f32 -> 2 bf16 in one u32 (RNE, matches f2b)
static __device__ __forceinline__ unsigned int cvtpk(float lo, float hi) {
  unsigned int r;
  asm("v_cvt_pk_bf16_f32 %0, %1, %2" : "=v"(r) : "v"(lo), "v"(hi));
  return r;
}

// ---------------- prep (+sortk merged): fold BN, convert bf16, sort --------
// blocks 0..511: weight prep (fragment-major; see R8 notes).
// blocks 512..543: per-batch counting sort (batch = blockIdx.x - 512),
// also emits clid[b*NN+pos] = cluster of sorted position.
__global__ void prep(const float* W1, const float* b1, const float* g1, const float* be1,
                     const float* m1, const float* v1,
                     const float* W2, const float* W3, const float* b3, const float* W4,
                     const float* g2, const float* be2, const float* m2, const float* v2,
                     const int* choice,
                     float* W1f, float* bco,
                     unsigned short* W2b, unsigned short* W3s, unsigned short* W3ls,
                     unsigned short* W4b,
                     int* ord, int* seg, int* clid)
{
  __shared__ int hist[KK];
  __shared__ int base[KK];
  int t = threadIdx.x;

  if (blockIdx.x < 512) {
    int i = blockIdx.x * blockDim.x + t;
    const int T = 512 * 256;
    for (int d = i; d < 128; d += T) {
      float s1 = g1[d] / sqrtf(v1[d] + EPSB);
      W1f[d*4+0] = s1 * W1[d*3+0];
      W1f[d*4+1] = s1 * W1[d*3+1];
      W1f[d*4+2] = s1 * W1[d*3+2];
      W1f[d*4+3] = s1 * (b1[d] - m1[d]) + be1[d];
    }
    for (int n = i; n < 512; n += T) {
      float s = g2[n] / sqrtf(v2[n] + EPSB);
      bco[n] = s * b3[n] + be2[n] - s * m2[n];   // BN2 shift + scaled conv bias
    }
    for (int x = i; x < 256*128; x += T) {
      int c = x >> 7, kk = x & 127;
      int lane = (((kk & 31) >> 3) << 4) | (c & 15);
      int frag = (c >> 4) * 4 + (kk >> 5);
      W2b[frag*512 + lane*8 + (kk & 7)] = f2b(W2[x]);
    }
    for (int x = i; x < 512*256; x += T) {
      int n = x >> 8, kk = x & 255;
      float s = g2[n] / sqrtf(v2[n] + EPSB);
      int lane = (((kk & 31) >> 3) << 4) | (n & 15);
      int frag = (n >> 4) * 8 + (kk >> 5);
      W3s[frag*512 + lane*8 + (kk & 7)] = f2b(s * W3[n*512 + 256 + kk]);
      W3ls[x] = f2b(s * W3[n*512 + kk]);         // left half, row-major (k_dv)
    }
    for (int x = i; x < 384*512; x += T) {
      int n = x >> 9, kk = x & 511;
      int lane = (((kk & 31) >> 3) << 4) | (n & 15);
      int frag = (n >> 4) * 16 + (kk >> 5);
      W4b[frag*512 + lane*8 + (kk & 7)] = f2b(W4[x]);
    }
  } else {
    int b = blockIdx.x - 512;
    if (t < KK) hist[t] = 0;
    __syncthreads();
    for (int i = t; i < NN; i += blockDim.x) atomicAdd(&hist[choice[b*NN + i]], 1);
    __syncthreads();
    if (t == 0) {
      int acc = 0;
      for (int k = 0; k < KK; ++k) { base[k] = acc; seg[b*(KK+1)+k] = acc; acc += hist[k]; }
      seg[b*(KK+1)+KK] = acc;   // == NN
    }
    __syncthreads();
    for (int i = t; i < NN; i += blockDim.x) {
      int c = choice[b*NN + i];
      int pos = atomicAdd(&base[c], 1);
      ord[b*NN + pos] = i;
      clid[b*NN + pos] = c;
    }
  }
}

// ---------------- k_feat: xyz -> h128 (BN,ReLU) -> feat 256 (bf16, sorted) --
// GEMM2 swapped; outputs staged in LDS hO then flushed lane-contiguous.
// FUSED fg-partials: block straddles <=2 clusters (sorted, sizes >=~100);
// per-segment channel max reduced in-register (pf loop + shfl over lrow),
// written to pm[blk][2][256] + ids[blk][2]. Replaces k_fg's 128MB re-read.
__global__ __launch_bounds__(256) void k_feat(const float* __restrict__ xyz,
                                              const int* __restrict__ ord,
                                              const int* __restrict__ clid,
                                              const int* __restrict__ seg,
                                              const float* __restrict__ W1f,
                                              const unsigned short* __restrict__ W2b,
                                              const float* __restrict__ b2,
                                              unsigned short* __restrict__ feat,
                                              unsigned short* __restrict__ pm,
                                              int* __restrict__ ids)
{
  __shared__ float lW1[128*4];
  __shared__ __align__(16) char hA[64*256];   // 64 rows x 128 bf16, XOR-swizzled
  __shared__ __align__(16) char hO[64*512];   // 64 rows x 256 bf16, XOR-swizzled
  int t = threadIdx.x;
  int b = blockIdx.x >> 7;            // 128 blocks per batch
  int posbase = (blockIdx.x & 127) * 64;
  if (t < 128) ((f32x4*)lW1)[t] = ((const f32x4*)W1f)[t];
  __syncthreads();

  {
    int r = t >> 2;
    int q = t & 3;
    int p = ord[b*NN + posbase + r];
    const float* xp = xyz + (size_t)(b*NN + p)*3;
    float x0 = xp[0], x1 = xp[1], x2 = xp[2];
#pragma unroll
    for (int dd = 0; dd < 32; dd += 2) {
      int d = q*32 + dd;
      f32x4 w0 = ((const f32x4*)lW1)[d];
      f32x4 w1 = ((const f32x4*)lW1)[d+1];
      float v0 = fmaxf(fmaf(x2, w0[2], fmaf(x1, w0[1], fmaf(x0, w0[0], w0[3]))), 0.0f);
      float v1 = fmaxf(fmaf(x2, w1[2], fmaf(x1, w1[1], fmaf(x0, w1[0], w1[3]))), 0.0f);
      unsigned int pk = cvtpk(v0, v1);
      int byte = ((r*128 + d)*2) ^ ((r & 7) << 4);
      *(unsigned int*)(hA + byte) = pk;
    }
  }
  __syncthreads();

  int lane = t & 63, w = t >> 6;
  int lrow = lane & 15, lhi = lane >> 4;
  f32x4 acc[4][4];   // [cf][pf]
#pragma unroll
  for (int cf = 0; cf < 4; ++cf)
#pragma unroll
    for (int pf = 0; pf < 4; ++pf) acc[cf][pf] = (f32x4)0.0f;

#pragma unroll
  for (int ks = 0; ks < 4; ++ks) {
    int k0 = ks*32 + lhi*8;
    bf16x8 haf[4];
#pragma unroll
    for (int pf = 0; pf < 4; ++pf) {
      int row = pf*16 + lrow;
      int byte = ((row*128 + k0)*2) ^ ((row & 7) << 4);
      haf[pf] = *(const bf16x8*)(hA + byte);
    }
    bf16x8 wf[4];
#pragma unroll
    for (int cf = 0; cf < 4; ++cf) {
      int frag = ((w*4 + cf)*4 + ks);
      wf[cf] = *(const bf16x8*)(W2b + frag*512 + lane*8);
    }
#pragma unroll
    for (int cf = 0; cf < 4; ++cf)
#pragma unroll
      for (int pf = 0; pf < 4; ++pf)
        acc[cf][pf] = __builtin_amdgcn_mfma_f32_16x16x32_bf16(wf[cf], haf[pf], acc[cf][pf], 0, 0, 0);
  }

  // segment boundary: rows [0,r0) in cluster c0, [r0,64) in cluster c1
  int c0 = clid[b*NN + posbase];
  int c1 = clid[b*NN + posbase + 63];
  int r0 = (c0 == c1) ? 64 : (seg[b*(KK+1) + c1] - posbase);

  float mA[4][4], mB[4][4];
#pragma unroll
  for (int cf = 0; cf < 4; ++cf)
#pragma unroll
    for (int rr = 0; rr < 4; ++rr) { mA[cf][rr] = -1e30f; mB[cf][rr] = -1e30f; }

  // epilogue: lane holds c = w*64+cf*16+4*lhi+rr at point pf*16+lrow -> hO LDS
#pragma unroll
  for (int cf = 0; cf < 4; ++cf) {
    int c0ch = w*64 + cf*16 + 4*lhi;
    f32x4 bv = *(const f32x4*)(b2 + c0ch);
#pragma unroll
    for (int pf = 0; pf < 4; ++pf) {
      int row = pf*16 + lrow;
      float v0 = acc[cf][pf][0] + bv[0];
      float v1 = acc[cf][pf][1] + bv[1];
      float v2 = acc[cf][pf][2] + bv[2];
      float v3 = acc[cf][pf][3] + bv[3];
      u32x2 pk;
      pk[0] = cvtpk(v0, v1);
      pk[1] = cvtpk(v2, v3);
      int byte = (row*512 + c0ch*2) ^ ((row & 7) << 4);
      *(u32x2*)(hO + byte) = pk;
      if (row >= r0) {
        mB[cf][0] = fmaxf(mB[cf][0], v0); mB[cf][1] = fmaxf(mB[cf][1], v1);
        mB[cf][2] = fmaxf(mB[cf][2], v2); mB[cf][3] = fmaxf(mB[cf][3], v3);
      } else {
        mA[cf][0] = fmaxf(mA[cf][0], v0); mA[cf][1] = fmaxf(mA[cf][1], v1);
        mA[cf][2] = fmaxf(mA[cf][2], v2); mA[cf][3] = fmaxf(mA[cf][3], v3);
      }
    }
  }

  // cross-lane reduce over lrow (16 lanes within each lhi group)
#pragma unroll
  for (int cf = 0; cf < 4; ++cf)
#pragma unroll
    for (int rr = 0; rr < 4; ++rr) {
      float a = mA[cf][rr], bb = mB[cf][rr];
#pragma unroll
      for (int off = 1; off < 16; off <<= 1) {
        a  = fmaxf(a,  __shfl_xor(a,  off, 64));
        bb = fmaxf(bb, __shfl_xor(bb, off, 64));
      }
      mA[cf][rr] = a; mB[cf][rr] = bb;
    }
  if (lrow == 0) {
#pragma unroll
    for (int cf = 0; cf < 4; ++cf) {
      int ch = w*64 + cf*16 + 4*lhi;
      u32x2 pkA, pkB;
      pkA[0] = cvtpk(mA[cf][0], mA[cf][1]); pkA[1] = cvtpk(mA[cf][2], mA[cf][3]);
      pkB[0] = cvtpk(mB[cf][0], mB[cf][1]); pkB[1] = cvtpk(mB[cf][2], mB[cf][3]);
      *(u32x2*)(pm + (size_t)blockIdx.x*512 + ch)       = pkA;
      *(u32x2*)(pm + (size_t)blockIdx.x*512 + 256 + ch) = pkB;
    }
  }
  if (t == 0) { ids[blockIdx.x*2] = c0; ids[blockIdx.x*2+1] = c1; }
  __syncthreads();

  // lane-contiguous flush: instr cc of wave w covers 1KB contiguous global
#pragma unroll
  for (int cc = 0; cc < 8; ++cc) {
    int lin = w*8192 + cc*1024 + lane*16;
    int row = lin >> 9;
    int off = lin & 511;
    int src = (row*512 + off) ^ ((row & 7) << 4);
    u32x4 v = *(const u32x4*)(hO + src);
    __builtin_nontemporal_store(v,
        (u32x4*)((char*)(feat + (size_t)(b*NN + posbase + row)*256) + off));
  }
}

// ---------------- k_fg: reduce per-block partials -> fg bf16 ----------------
// cluster (b,k) spans feat-blocks [ (b*NN+s)>>6, (b*NN+e-1)>>6 ] (~3 blocks);
// thread = channel; max over matching segments. Reads 4MB instead of 128MB.
__global__ __launch_bounds__(256) void k_fg(const unsigned short* __restrict__ pm,
                                            const int* __restrict__ ids,
                                            const int* __restrict__ seg,
                                            unsigned short* __restrict__ fg)
{
  int blk = blockIdx.x;
  int b = blk >> 6, k = blk & 63;
  int s = seg[b*(KK+1)+k], e = seg[b*(KK+1)+k+1];
  int t = threadIdx.x;
  float m = -1e30f;
  if (e > s) {
    int g0 = (b*NN + s) >> 6;
    int g1 = (b*NN + e - 1) >> 6;
    for (int g = g0; g <= g1; ++g) {
      if (ids[g*2]   == k) m = fmaxf(m, b2f(pm[(size_t)g*512 + t]));
      if (ids[g*2+1] == k) m = fmaxf(m, b2f(pm[(size_t)g*512 + 256 + t]));
    }
  }
  fg[(b*KK + k)*256 + t] = f2b(m);
}

// ---------------- k_dv: Dv[2048][512] = fg @ W3ls^T + bco (MFMA GEMM) -------
__global__ __launch_bounds__(256) void k_dv(const unsigned short* __restrict__ fg,
                                            const unsigned short* __restrict__ W3ls,
                                            const float* __restrict__ bco,
                                            float* __restrict__ Dv)
{
  __shared__ __align__(16) char As[32*512];   // 32 rows x 256 bf16, swizzled
  int t = threadIdx.x;
  int row0 = blockIdx.x * 32;
  {
    int r = t >> 3;
    const char* src = (const char*)(fg + (size_t)(row0 + r)*256);
    int cbase = (t & 7) * 16;
#pragma unroll
    for (int cc = 0; cc < 4; ++cc) {
      int byteoff = cbase + cc*128;
      int dst = (r*512 + byteoff) ^ ((r & 7) << 4);
      *(u32x4*)(As + dst) = *(const u32x4*)(src + byteoff);
    }
  }
  __syncthreads();

  int lane = t & 63, w = t >> 6;
  int lrow = lane & 15, lhi = lane >> 4;

  f32x4 acc[2][8];
#pragma unroll
  for (int m = 0; m < 2; ++m)
#pragma unroll
    for (int nt = 0; nt < 8; ++nt) acc[m][nt] = (f32x4)0.0f;

#pragma unroll 2
  for (int ks = 0; ks < 8; ++ks) {
    int koff = ks*32 + lhi*8;
    bf16x8 af[2];
#pragma unroll
    for (int m = 0; m < 2; ++m) {
      int row = m*16 + lrow;
      int byte = (row*512 + koff*2) ^ ((row & 7) << 4);
      af[m] = *(const bf16x8*)(As + byte);
    }
    bf16x8 bf[8];
#pragma unroll
    for (int nt = 0; nt < 8; ++nt) {
      int n = w*128 + nt*16 + lrow;
      bf[nt] = *(const bf16x8*)(W3ls + n*256 + koff);
    }
#pragma unroll
    for (int m = 0; m < 2; ++m)
#pragma unroll
      for (int nt = 0; nt < 8; ++nt)
        acc[m][nt] = __builtin_amdgcn_mfma_f32_16x16x32_bf16(af[m], bf[nt], acc[m][nt], 0, 0, 0);
  }

#pragma unroll
  for (int m = 0; m < 2; ++m)
#pragma unroll
    for (int nt = 0; nt < 8; ++nt) {
      int n = w*128 + nt*16 + lrow;
      float bc = bco[n];
#pragma unroll
      for (int rr = 0; rr < 4; ++rr) {
        int row = m*16 + lhi*4 + rr;
        Dv[(size_t)(row0 + row)*512 + n] = acc[m][nt][rr] + bc;
      }
    }
}

// ---------------- k_out: per-(b,k) fused GEMM3' + BN + ReLU + GEMM4 + max ---
// R21-best: 512 threads (8 waves), M=48, VGPR<=64 (launch_bounds(512,8)),
// 2 blocks/CU, padded linear LDS (base VGPR + imm offsets).
__global__ __launch_bounds__(512, 8) void k_out(const unsigned short* __restrict__ feat,
                                                const int* __restrict__ seg,
                                                const float* __restrict__ Dv,
                                                const unsigned short* __restrict__ W3s,
                                                const unsigned short* __restrict__ W4b,
                                                const float* __restrict__ b4,
                                                float* __restrict__ out)
{
  __shared__ float Dvs[512];
  __shared__ float rm[OUTC];
  __shared__ __align__(16) char As[48*AS_STRIDE];    // 24.75KB
  __shared__ __align__(16) char Mid[48*MID_STRIDE];  // 48.75KB
  int blk = blockIdx.x;
  int b = blk >> 6, k = blk & 63;
  int t = threadIdx.x;
  int s = seg[b*(KK+1)+k], e = seg[b*(KK+1)+k+1];
  int S = e - s;

  Dvs[t] = Dv[(size_t)(b*KK + k)*512 + t];
  if (t < OUTC) rm[t] = -1e30f;

  int lane = t & 63, w = t >> 6;
  int lrow = lane & 15, lhi = lane >> 4;

  // linear LDS bases (1 VGPR each; all per-access variation is imm offsets)
  int baseA = lrow*AS_STRIDE + lhi*16;                 // G3 As reads
  int baseM = lrow*MID_STRIDE + lhi*16;                // G4 Mid reads
  int baseW = lrow*MID_STRIDE + w*128 + lhi*8;         // G3 Mid writes

  // stage helpers: 48 rows x 32 chunks(16B) = 1536 chunks; 3 per thread
  int lim = b*NN + NN - 1;
  int srow[3], sdst[3], soff[3];
#pragma unroll
  for (int j = 0; j < 3; ++j) {
    int c = t + j*512;
    srow[j] = c >> 5;
    soff[j] = (c & 31) * 16;
    sdst[j] = srow[j]*AS_STRIDE + soff[j];
  }

  // prologue: stage tile 0
#pragma unroll
  for (int j = 0; j < 3; ++j) {
    int pos = b*NN + s + srow[j];
    if (pos > lim) pos = lim;
    const char* src = (const char*)(feat + (size_t)pos*256);
    u32x4 v = __builtin_nontemporal_load((const u32x4*)(src + soff[j]));
    *(u32x4*)(As + sdst[j]) = v;
  }

  for (int mt = 0; mt < S; mt += 48) {
    __syncthreads();   // As(tile) staged; Mid free (prev G4 done)

    // GEMM3': Mid[48][512] = relu(W3s @ As^T + Dv)^T, wave w owns n [w*64,+64)
#pragma unroll 1
    for (int g = 0; g < 2; ++g) {
      f32x4 acc2[2][3];   // [nf][pf]
#pragma unroll
      for (int nf = 0; nf < 2; ++nf)
#pragma unroll
        for (int pf = 0; pf < 3; ++pf) acc2[nf][pf] = (f32x4)0.0f;

#pragma unroll 1
      for (int ks = 0; ks < 8; ++ks) {
        bf16x8 asf[3];
#pragma unroll
        for (int pf = 0; pf < 3; ++pf)
          asf[pf] = *(const bf16x8*)(As + (baseA + ks*64 + pf*(16*AS_STRIDE)));
        bf16x8 w3f[2];
#pragma unroll
        for (int nf = 0; nf < 2; ++nf) {
          int frag = (w*4 + g*2 + nf)*8 + ks;
          w3f[nf] = *(const bf16x8*)(W3s + frag*512 + lane*8);
        }
        __builtin_amdgcn_s_setprio(1);
#pragma unroll
        for (int nf = 0; nf < 2; ++nf)
#pragma unroll
          for (int pf = 0; pf < 3; ++pf)
            acc2[nf][pf] = __builtin_amdgcn_mfma_f32_16x16x32_bf16(w3f[nf], asf[pf], acc2[nf][pf], 0, 0, 0);
        __builtin_amdgcn_s_setprio(0);
      }

      // epilogue: lane holds n = w*64+(g*2+nf)*16+4*lhi+rr at point pf*16+lrow
#pragma unroll
      for (int nf = 0; nf < 2; ++nf) {
        int n0 = w*64 + (g*2 + nf)*16 + 4*lhi;
        f32x4 d4 = *(const f32x4*)(Dvs + n0);
#pragma unroll
        for (int pf = 0; pf < 3; ++pf) {
          float v0 = fmaxf(acc2[nf][pf][0] + d4[0], 0.0f);
          float v1 = fmaxf(acc2[nf][pf][1] + d4[1], 0.0f);
          float v2 = fmaxf(acc2[nf][pf][2] + d4[2], 0.0f);
          float v3 = fmaxf(acc2[nf][pf][3] + d4[3], 0.0f);
          u32x2 pk;
          pk[0] = cvtpk(v0, v1);
          pk[1] = cvtpk(v2, v3);
          *(u32x2*)(Mid + (baseW + (g*2 + nf)*32 + pf*(16*MID_STRIDE))) = pk;
        }
      }
    }
    __syncthreads();   // Mid ready; As free

    // stage tile i+1 directly into As (overlaps G4 via wave scheduling)
    if (mt + 48 < S) {
#pragma unroll
      for (int j = 0; j < 3; ++j) {
        int pos = b*NN + s + mt + 48 + srow[j];
        if (pos > lim) pos = lim;
        const char* src = (const char*)(feat + (size_t)pos*256);
        u32x4 v = __builtin_nontemporal_load((const u32x4*)(src + soff[j]));
        *(u32x4*)(As + sdst[j]) = v;
      }
    }

    // GEMM4: out[48][384], wave w cols [w*48,+48); fold max into rm[]
    {
      f32x4 acc4[3][3];
#pragma unroll
      for (int m = 0; m < 3; ++m)
#pragma unroll
        for (int nt = 0; nt < 3; ++nt) acc4[m][nt] = (f32x4)0.0f;

#pragma unroll 1
      for (int ks = 0; ks < 16; ++ks) {
        bf16x8 af[3];
#pragma unroll
        for (int m = 0; m < 3; ++m)
          af[m] = *(const bf16x8*)(Mid + (baseM + ks*64 + m*(16*MID_STRIDE)));
        __builtin_amdgcn_s_setprio(1);
#pragma unroll
        for (int nt = 0; nt < 3; ++nt) {
          int frag = (w*3 + nt)*16 + ks;
          bf16x8 bf = *(const bf16x8*)(W4b + frag*512 + lane*8);
#pragma unroll
          for (int m = 0; m < 3; ++m)
            acc4[m][nt] = __builtin_amdgcn_mfma_f32_16x16x32_bf16(af[m], bf, acc4[m][nt], 0, 0, 0);
        }
        __builtin_amdgcn_s_setprio(0);
      }

      // per-tile max: reduce rows of this tile, RMW by owner lane (disjoint cols/wave)
#pragma unroll
      for (int nt = 0; nt < 3; ++nt) {
        float v = -1e30f;
#pragma unroll
        for (int m = 0; m < 3; ++m)
#pragma unroll
          for (int rr = 0; rr < 4; ++rr) {
            int rowg = mt + m*16 + lhi*4 + rr;
            v = (rowg < S) ? fmaxf(v, acc4[m][nt][rr]) : v;
          }
        v = fmaxf(v, __shfl_xor(v, 16, 64));
        v = fmaxf(v, __shfl_xor(v, 32, 64));
        if (lane < 16) {
          int col = w*48 + nt*16 + lrow;
          rm[col] = fmaxf(rm[col], v);
        }
      }
    }
  }
  __syncthreads();

  if (t < OUTC) out[(b*KK + k)*OUTC + t] = rm[t] + b4[t];
}

extern "C" void kernel_launch(void* const* d_in, const int* in_sizes, int n_in,
                              void* d_out, int out_size, void* d_ws, size_t ws_size,
                              hipStream_t stream)
{
  const float* xyz   = (const float*)d_in[0];
  const int*   choice= (const int*)  d_in[1];
  const float* W1    = (const float*)d_in[2];
  const float* b1    = (const float*)d_in[3];
  const float* g1    = (const float*)d_in[4];
  const float* be1   = (const float*)d_in[5];
  const float* m1    = (const float*)d_in[6];
  const float* v1    = (const float*)d_in[7];
  const float* W2    = (const float*)d_in[8];
  const float* b2    = (const float*)d_in[9];
  const float* W3    = (const float*)d_in[10];
  const float* b3    = (const float*)d_in[11];
  const float* g2    = (const float*)d_in[12];
  const float* be2   = (const float*)d_in[13];
  const float* m2    = (const float*)d_in[14];
  const float* v2    = (const float*)d_in[15];
  const float* W4    = (const float*)d_in[16];
  const float* b4    = (const float*)d_in[17];

  char* ws = (char*)d_ws;
  size_t o = 0;
  int* ord             = (int*)(ws + o);            o += (size_t)BB*NN*4;       // 1 MB
  int* clid            = (int*)(ws + o);            o += (size_t)BB*NN*4;       // 1 MB
  int* seg             = (int*)(ws + o);            o += 64*1024;
  float* W1f           = (float*)(ws + o);          o += 4*1024;
  float* bco           = (float*)(ws + o);          o += 4*1024;
  unsigned short* W2b  = (unsigned short*)(ws + o); o += (size_t)256*128*2;
  unsigned short* W3s  = (unsigned short*)(ws + o); o += (size_t)512*256*2;
  unsigned short* W3ls = (unsigned short*)(ws + o); o += (size_t)512*256*2;
  unsigned short* W4b  = (unsigned short*)(ws + o); o += (size_t)384*512*2;
  unsigned short* fg   = (unsigned short*)(ws + o); o += (size_t)BB*KK*256*2;   // 1 MB
  unsigned short* pm   = (unsigned short*)(ws + o); o += (size_t)4096*512*2;    // 4 MB
  int* ids             = (int*)(ws + o);            o += (size_t)4096*2*4;      // 32 KB
  float* Dv            = (float*)(ws + o);          o += (size_t)BB*KK*512*4;   // 4 MB
  unsigned short* feat = (unsigned short*)(ws + o); o += (size_t)BB*NN*256*2;   // 128 MB

  prep<<<544, 256, 0, stream>>>(W1, b1, g1, be1, m1, v1, W2, W3, b3, W4,
                                g2, be2, m2, v2, choice,
                                W1f, bco, W2b, W3s, W3ls, W4b, ord, seg, clid);
  k_feat<<<BB*NN/64, 256, 0, stream>>>(xyz, ord, clid, seg, W1f, W2b, b2,
                                       feat, pm, ids);
  k_fg<<<BB*KK, 256, 0, stream>>>(pm, ids, seg, fg);
  k_dv<<<BB*KK/32, 256, 0, stream>>>(fg, W3ls, bco, Dv);
  k_out<<<BB*KK, 512, 0, stream>>>(feat, seg, Dv, W3s, W4b, b4, (float*)d_out);
}